// Round 2
// baseline (317.698 us; speedup 1.0000x reference)
//
#include <hip/hip_runtime.h>
#include <math.h>

namespace {

constexpr int H = 2048;
constexpr int W = 2048;
constexpr int HW = H * W;
constexpr float TANH_C  = 1.1486328125f;
constexpr float DEG2RAD = 0.017453292519943295f; // np.float32(pi/180)
constexpr float RT2H    = 0.70710678118654752f;  // sqrt(2)/2
constexpr float LOG2E   = 1.4426950408889634f;   // log2(e)
constexpr float TWOPI   = 6.283185307179586f;

// --- guarded HW-transcendental wrappers (single VALU op each) ---
__device__ __forceinline__ float fexp2(float x) {
#if __has_builtin(__builtin_amdgcn_exp2f)
    return __builtin_amdgcn_exp2f(x);          // v_exp_f32: 2^x
#else
    return __exp2f(x);
#endif
}
__device__ __forceinline__ float fcos_rev(float x) {  // cos(2*pi*x)
#if __has_builtin(__builtin_amdgcn_cosf)
    return __builtin_amdgcn_cosf(x);           // v_cos_f32: revolutions
#else
    return __cosf(x * TWOPI);
#endif
}
__device__ __forceinline__ float fsin_rev(float x) {  // sin(2*pi*x)
#if __has_builtin(__builtin_amdgcn_sinf)
    return __builtin_amdgcn_sinf(x);
#else
    return __sinf(x * TWOPI);
#endif
}
__device__ __forceinline__ float frcp(float x) {
#if __has_builtin(__builtin_amdgcn_rcpf)
    return __builtin_amdgcn_rcpf(x);           // v_rcp_f32
#else
    return 1.0f / x;
#endif
}

// out layout: [0,HW) p_ignite, [HW,2HW) new_burning (0/1), [2HW,3HW) new_burned
// 4 cells/thread: block = 256 threads covers 1024 cols x 1 row.
__global__ __launch_bounds__(256) void wildfire_step(
    const float* __restrict__ p_veg,  const float* __restrict__ p_den,
    const float* __restrict__ wind_v, const float* __restrict__ wind_d,
    const float* __restrict__ slope,
    const float* __restrict__ s_a,  const float* __restrict__ s_ph,
    const float* __restrict__ s_c1, const float* __restrict__ s_c2,
    const float* __restrict__ s_pc,
    const float* __restrict__ rand_ig, const float* __restrict__ rand_co,
    const int* __restrict__ burning, const int* __restrict__ burned,
    float* __restrict__ out)
{
    __shared__ __align__(16) float sb[3][1032];  // halo: cols j0-1 .. j0+1024
    const int t  = (int)threadIdx.x;
    const int i  = (int)blockIdx.y;
    const int j0 = (int)blockIdx.x * 1024;

    for (int r = 0; r < 3; ++r) {
        const int ii = i + r - 1;
        for (int c = t; c < 1026; c += 256) {
            const int jj = j0 - 1 + c;
            float v = 0.f;
            if (ii >= 0 && ii < H && jj >= 0 && jj < W)
                v = burning[ii * W + jj] ? 1.f : 0.f;
            sb[r][c] = v;
        }
    }
    __syncthreads();

    const int jb  = t * 4;            // local col of first owned cell
    const int idx = i * W + j0 + jb;  // idx % 4 == 0 -> 16B-aligned vec accesses

    // 8-wide burning windows from two ds_read_b128 per row (static extraction)
    float r0[8], r1[8], r2[8];
    {
        const float4 a0 = *reinterpret_cast<const float4*>(&sb[0][jb]);
        const float4 a1 = *reinterpret_cast<const float4*>(&sb[0][jb + 4]);
        const float4 b0 = *reinterpret_cast<const float4*>(&sb[1][jb]);
        const float4 b1 = *reinterpret_cast<const float4*>(&sb[1][jb + 4]);
        const float4 c0 = *reinterpret_cast<const float4*>(&sb[2][jb]);
        const float4 c1 = *reinterpret_cast<const float4*>(&sb[2][jb + 4]);
        r0[0]=a0.x; r0[1]=a0.y; r0[2]=a0.z; r0[3]=a0.w; r0[4]=a1.x; r0[5]=a1.y; r0[6]=a1.z; r0[7]=a1.w;
        r1[0]=b0.x; r1[1]=b0.y; r1[2]=b0.z; r1[3]=b0.w; r1[4]=b1.x; r1[5]=b1.y; r1[6]=b1.z; r1[7]=b1.w;
        r2[0]=c0.x; r2[1]=c0.y; r2[2]=c0.z; r2[3]=c0.w; r2[4]=c1.x; r2[5]=c1.y; r2[6]=c1.z; r2[7]=c1.w;
    }

    float anyn[4], pig[4];
    bool  isb[4], ni[4];
#pragma unroll
    for (int x = 0; x < 4; ++x) {
        anyn[x] = ((r0[x] + r0[x+1]) + (r0[x+2] + r1[x]))
                + ((r1[x+2] + r2[x]) + (r2[x+1] + r2[x+2]));
        isb[x]  = (r1[x+1] != 0.f);
        pig[x]  = 0.f;
        ni[x]   = false;
    }

    const int4  burned4 = *reinterpret_cast<const int4*>(burned + idx);
    const int   bn[4]   = {burned4.x, burned4.y, burned4.z, burned4.w};
    const float p_cont  = s_pc[0];

    // rand_co consumed only by burning cells (~1%) — gate its fetch
    float rc[4] = {0.f, 0.f, 0.f, 0.f};
    if (isb[0] || isb[1] || isb[2] || isb[3]) {
        const float4 rco4 = *reinterpret_cast<const float4*>(rand_co + idx);
        rc[0]=rco4.x; rc[1]=rco4.y; rc[2]=rco4.z; rc[3]=rco4.w;
    }

    // heavy-field fetch gated per lane-group (~17% of groups); exec-masked
    // lanes issue no memory requests.
    if ((anyn[0] + anyn[1] + anyn[2] + anyn[3]) != 0.f) {
        const float a_  = s_a[0];
        const float p_h = s_ph[0];
        const float c1  = s_c1[0];
        const float c2  = s_c2[0];

        const float4 pv4  = *reinterpret_cast<const float4*>(p_veg  + idx);
        const float4 pd4  = *reinterpret_cast<const float4*>(p_den  + idx);
        const float4 wv4  = *reinterpret_cast<const float4*>(wind_v + idx);
        const float4 wd4  = *reinterpret_cast<const float4*>(wind_d + idx);
        const float4 rig4 = *reinterpret_cast<const float4*>(rand_ig + idx);
        const float pv[4]  = {pv4.x, pv4.y, pv4.z, pv4.w};
        const float pd[4]  = {pd4.x, pd4.y, pd4.z, pd4.w};
        const float wv[4]  = {wv4.x, wv4.y, wv4.z, wv4.w};
        const float wd[4]  = {wd4.x, wd4.y, wd4.z, wd4.w};
        const float rig[4] = {rig4.x, rig4.y, rig4.z, rig4.w};

        float sl[36];   // 144B, 16B-aligned (idx%4==0 -> idx*36 % 16 == 0)
        __builtin_memcpy(sl, slope + (size_t)idx * 9, 36 * sizeof(float));

        const float aslL = (a_ * DEG2RAD) * LOG2E;

#pragma unroll
        for (int x = 0; x < 4; ++x) {
            if (anyn[x] != 0.f) {
                // revolutions for HW sin/cos: wd/360
                const float wrev = wd[x] * (1.f / 360.f);
                const float cw = fcos_rev(wrev);
                const float sw = fsin_rev(wrev);

                const float Lc2wv = (LOG2E * c2) * wv[x];
                const float cwv = Lc2wv * cw, swv = Lc2wv * sw;
                const float cwr = RT2H * cwv, swr = RT2H * swv;
                const float dpl = cwr + swr;   //  45 deg
                const float dmi = cwr - swr;   // 315 deg
                const float p_base = (p_h * (1.f + pv[x])) * (1.f + pd[x]);
                const float Cz2 = (2.f * LOG2E * TANH_C) * p_base
                                * fexp2(LOG2E * (c1 * wv[x] - c2 * wv[x]));
                const float* s = sl + 9 * x;

#define NEIGHBOR(K, b, T, sv)                                            \
                const float q##K = fmaf(aslL, (sv), (T));                \
                const float z##K = Cz2 * fexp2(q##K);                    \
                const float E##K = fexp2(z##K);                          \
                const float d##K = fmaf((b), E##K, 1.f);

                NEIGHBOR(0, r0[x],    dmi, s[0])   // 315
                NEIGHBOR(1, r0[x+1], -swv, s[1])   // 270
                NEIGHBOR(2, r0[x+2], -dpl, s[2])   // 225
                NEIGHBOR(3, r1[x],    cwv, s[3])   //   0
                NEIGHBOR(5, r1[x+2], -cwv, s[5])   // 180
                NEIGHBOR(6, r2[x],    dpl, s[6])   //  45
                NEIGHBOR(7, r2[x+1],  swv, s[7])   //  90
                NEIGHBOR(8, r2[x+2], -dmi, s[8])   // 135
#undef NEIGHBOR
                const float den = ((d0 * d1) * (d2 * d3)) * ((d5 * d6) * (d7 * d8));
                const float num = fexp2(anyn[x]);         // 2^(#burning nbrs), exact
                pig[x] = fmaf(-num, frcp(den), 1.f);

                ni[x] = (!isb[x]) && (bn[x] == 0) && (rig[x] < pig[x]);
            }
        }
    }

    float4 o0, o1, o2;
    float* o0p = &o0.x; float* o1p = &o1.x; float* o2p = &o2.x;
#pragma unroll
    for (int x = 0; x < 4; ++x) {
        const bool keep = isb[x] && (rc[x] < p_cont);
        const bool nb   = ni[x] || keep;
        const bool nd   = (bn[x] != 0) || (isb[x] && !keep);
        o0p[x] = pig[x];
        o1p[x] = nb ? 1.f : 0.f;
        o2p[x] = nd ? 1.f : 0.f;
    }
    *reinterpret_cast<float4*>(out + idx)          = o0;
    *reinterpret_cast<float4*>(out + HW + idx)     = o1;
    *reinterpret_cast<float4*>(out + 2 * HW + idx) = o2;
}

} // namespace

extern "C" void kernel_launch(void* const* d_in, const int* in_sizes, int n_in,
                              void* d_out, int out_size, void* d_ws, size_t ws_size,
                              hipStream_t stream)
{
    (void)in_sizes; (void)n_in; (void)out_size; (void)d_ws; (void)ws_size;
    dim3 grid(W / 1024, H, 1);
    dim3 block(256, 1, 1);
    hipLaunchKernelGGL(wildfire_step, grid, block, 0, stream,
        (const float*)d_in[0],  (const float*)d_in[1],
        (const float*)d_in[2],  (const float*)d_in[3],
        (const float*)d_in[4],
        (const float*)d_in[5],  (const float*)d_in[6],
        (const float*)d_in[7],  (const float*)d_in[8],
        (const float*)d_in[9],
        (const float*)d_in[10], (const float*)d_in[11],
        (const int*)d_in[12],   (const int*)d_in[13],
        (float*)d_out);
}

// Round 3
// 305.203 us; speedup vs baseline: 1.0409x; 1.0409x over previous
//
#include <hip/hip_runtime.h>
#include <math.h>

namespace {

constexpr int H = 2048;
constexpr int W = 2048;
constexpr int HW = H * W;
constexpr float TANH_C  = 1.1486328125f;
constexpr float DEG2RAD = 0.017453292519943295f; // np.float32(pi/180)
constexpr float RT2H    = 0.70710678118654752f;  // sqrt(2)/2
constexpr float LOG2E   = 1.4426950408889634f;   // log2(e)
constexpr float TWOPI   = 6.283185307179586f;

// --- guarded HW-transcendental wrappers (single VALU op each) ---
__device__ __forceinline__ float fexp2(float x) {
#if __has_builtin(__builtin_amdgcn_exp2f)
    return __builtin_amdgcn_exp2f(x);          // v_exp_f32: 2^x
#else
    return __exp2f(x);
#endif
}
__device__ __forceinline__ float fcos_rev(float x) {  // cos(2*pi*x)
#if __has_builtin(__builtin_amdgcn_cosf)
    return __builtin_amdgcn_cosf(x);           // v_cos_f32: revolutions
#else
    return __cosf(x * TWOPI);
#endif
}
__device__ __forceinline__ float fsin_rev(float x) {  // sin(2*pi*x)
#if __has_builtin(__builtin_amdgcn_sinf)
    return __builtin_amdgcn_sinf(x);
#else
    return __sinf(x * TWOPI);
#endif
}
__device__ __forceinline__ float frcp(float x) {
#if __has_builtin(__builtin_amdgcn_rcpf)
    return __builtin_amdgcn_rcpf(x);           // v_rcp_f32
#else
    return 1.0f / x;
#endif
}

// out layout: [0,HW) p_ignite, [HW,2HW) new_burning (0/1), [2HW,3HW) new_burned
// Block = 256 threads, tile = 1 row x 1024 cols (4 cells/thread).
// Heavy cells (any burning neighbor, ~8.6%) are COMPACTED into an LDS
// worklist so the transcendental path runs with dense lane occupancy
// (~1.4 waves/block) instead of exec-masked in every wave.
__global__ __launch_bounds__(256) void wildfire_step(
    const float* __restrict__ p_veg,  const float* __restrict__ p_den,
    const float* __restrict__ wind_v, const float* __restrict__ wind_d,
    const float* __restrict__ slope,
    const float* __restrict__ s_a,  const float* __restrict__ s_ph,
    const float* __restrict__ s_c1, const float* __restrict__ s_c2,
    const float* __restrict__ s_pc,
    const float* __restrict__ rand_ig, const float* __restrict__ rand_co,
    const int* __restrict__ burning, const int* __restrict__ burned,
    float* __restrict__ out)
{
    // sb[r][4+k] = burning(i+r-1, j0+k) for k in [-1, 1024]; float 0/1
    __shared__ __align__(16) float sb[3][1032];
    __shared__ __align__(16) float pig_lds[1024];
    __shared__ unsigned short q[1024];
    __shared__ int qn;

    const int t  = (int)threadIdx.x;
    const int i  = (int)blockIdx.y;
    const int j0 = (int)blockIdx.x * 1024;
    const int rowbase = i * W + j0;

    if (t == 0) qn = 0;

    // ---- Phase A: vectorized halo staging (int4 -> float 0/1) ----
    for (int r = 0; r < 3; ++r) {
        const int ii = i + r - 1;
        const bool rowok = (ii >= 0) && (ii < H);
        int4 v = make_int4(0, 0, 0, 0);
        if (rowok)
            v = *reinterpret_cast<const int4*>(burning + ii * W + j0 + 4 * t);
        float4 f;
        f.x = v.x ? 1.f : 0.f;  f.y = v.y ? 1.f : 0.f;
        f.z = v.z ? 1.f : 0.f;  f.w = v.w ? 1.f : 0.f;
        *reinterpret_cast<float4*>(&sb[r][4 + 4 * t]) = f;   // 16B-aligned
        if (t == 0)
            sb[r][3] = (rowok && j0 > 0) ?
                       (burning[ii * W + j0 - 1] ? 1.f : 0.f) : 0.f;
        if (t == 1)
            sb[r][4 + 1024] = (rowok && j0 + 1024 < W) ?
                       (burning[ii * W + j0 + 1024] ? 1.f : 0.f) : 0.f;
    }
    __syncthreads();

    const int jb = t * 4;                 // local col of first owned cell
    const int idx = rowbase + jb;         // idx % 4 == 0 -> 16B-aligned vecs

    // 6-wide windows per row: cols jb-1 .. jb+4 (1 aligned b128 + 2 b32 each)
    float r0[6], r1[6], r2[6];
    {
        const float4 a = *reinterpret_cast<const float4*>(&sb[0][4 + jb]);
        const float4 b = *reinterpret_cast<const float4*>(&sb[1][4 + jb]);
        const float4 c = *reinterpret_cast<const float4*>(&sb[2][4 + jb]);
        r0[0] = sb[0][3 + jb]; r0[1] = a.x; r0[2] = a.y; r0[3] = a.z; r0[4] = a.w; r0[5] = sb[0][8 + jb];
        r1[0] = sb[1][3 + jb]; r1[1] = b.x; r1[2] = b.y; r1[3] = b.z; r1[4] = b.w; r1[5] = sb[1][8 + jb];
        r2[0] = sb[2][3 + jb]; r2[1] = c.x; r2[2] = c.y; r2[3] = c.z; r2[4] = c.w; r2[5] = sb[2][8 + jb];
    }

    // ---- Phase B: activity detection + worklist push ----
    float anyn[4];
    bool  isb[4];
#pragma unroll
    for (int x = 0; x < 4; ++x) {
        anyn[x] = ((r0[x] + r0[x+1]) + (r0[x+2] + r1[x]))
                + ((r1[x+2] + r2[x]) + (r2[x+1] + r2[x+2]));
        isb[x]  = (r1[x+1] != 0.f);
        if (anyn[x] != 0.f) {
            const int pos = atomicAdd(&qn, 1);
            q[pos] = (unsigned short)(jb + x);
        }
    }
    *reinterpret_cast<float4*>(&pig_lds[jb]) = make_float4(0.f, 0.f, 0.f, 0.f);
    __syncthreads();

    // ---- Phase C: dense heavy-cell processing ----
    const int n = qn;
    for (int k = t; k < n; k += 256) {
        const int cell = (int)q[k];
        const int c    = 4 + cell;
        const float b0 = sb[0][c-1], b1 = sb[0][c], b2 = sb[0][c+1];
        const float b3 = sb[1][c-1],                b5 = sb[1][c+1];
        const float b6 = sb[2][c-1], b7 = sb[2][c], b8 = sb[2][c+1];
        const float cnt = ((b0 + b1) + (b2 + b3)) + ((b5 + b6) + (b7 + b8));

        const int gidx = rowbase + cell;
        const float pv = p_veg[gidx];
        const float pd = p_den[gidx];
        const float wv = wind_v[gidx];
        const float wd = wind_d[gidx];
        float sl[9];
        __builtin_memcpy(sl, slope + (size_t)gidx * 9, 9 * sizeof(float));

        const float a_  = s_a[0];
        const float p_h = s_ph[0];
        const float c1  = s_c1[0];
        const float c2  = s_c2[0];

        // revolutions for HW sin/cos: wd/360
        const float wrev = wd * (1.f / 360.f);
        const float cw = fcos_rev(wrev);
        const float sw = fsin_rev(wrev);

        const float Lc2wv = (LOG2E * c2) * wv;
        const float cwv = Lc2wv * cw, swv = Lc2wv * sw;
        const float cwr = RT2H * cwv, swr = RT2H * swv;
        const float dpl = cwr + swr;   //  45 deg
        const float dmi = cwr - swr;   // 315 deg
        const float aslL = (a_ * DEG2RAD) * LOG2E;
        const float p_base = (p_h * (1.f + pv)) * (1.f + pd);
        const float Cz2 = (2.f * LOG2E * TANH_C) * p_base
                        * fexp2(LOG2E * (c1 * wv - c2 * wv));

#define NEIGHBOR(K, b, T, sv)                                            \
        const float q##K = fmaf(aslL, (sv), (T));                        \
        const float z##K = Cz2 * fexp2(q##K);                            \
        const float E##K = fexp2(z##K);                                  \
        const float d##K = fmaf((b), E##K, 1.f);

        NEIGHBOR(0, b0,  dmi, sl[0])   // 315
        NEIGHBOR(1, b1, -swv, sl[1])   // 270
        NEIGHBOR(2, b2, -dpl, sl[2])   // 225
        NEIGHBOR(3, b3,  cwv, sl[3])   //   0
        NEIGHBOR(5, b5, -cwv, sl[5])   // 180
        NEIGHBOR(6, b6,  dpl, sl[6])   //  45
        NEIGHBOR(7, b7,  swv, sl[7])   //  90
        NEIGHBOR(8, b8, -dmi, sl[8])   // 135
#undef NEIGHBOR
        const float den = ((d0 * d1) * (d2 * d3)) * ((d5 * d6) * (d7 * d8));
        const float num = fexp2(cnt);             // 2^(#burning nbrs), exact
        pig_lds[cell] = fmaf(-num, frcp(den), 1.f);
    }
    __syncthreads();

    // ---- Phase D: dense vectorized finish ----
    const int4  burned4 = *reinterpret_cast<const int4*>(burned + idx);
    const int   bn[4]   = {burned4.x, burned4.y, burned4.z, burned4.w};
    const float p_cont  = s_pc[0];

    const float4 pig4 = *reinterpret_cast<const float4*>(&pig_lds[jb]);
    const float pig[4] = {pig4.x, pig4.y, pig4.z, pig4.w};

    float rc[4] = {1.f, 1.f, 1.f, 1.f};
    if (isb[0] || isb[1] || isb[2] || isb[3]) {
        const float4 rco4 = *reinterpret_cast<const float4*>(rand_co + idx);
        rc[0] = rco4.x; rc[1] = rco4.y; rc[2] = rco4.z; rc[3] = rco4.w;
    }
    float rig[4] = {1.f, 1.f, 1.f, 1.f};
    if ((anyn[0] + anyn[1]) + (anyn[2] + anyn[3]) != 0.f) {
        const float4 rig4 = *reinterpret_cast<const float4*>(rand_ig + idx);
        rig[0] = rig4.x; rig[1] = rig4.y; rig[2] = rig4.z; rig[3] = rig4.w;
    }

    float4 o0, o1, o2;
    float* o0p = &o0.x; float* o1p = &o1.x; float* o2p = &o2.x;
#pragma unroll
    for (int x = 0; x < 4; ++x) {
        const bool ni   = (!isb[x]) && (bn[x] == 0) && (rig[x] < pig[x]);
        const bool keep = isb[x] && (rc[x] < p_cont);
        const bool nb   = ni || keep;
        const bool nd   = (bn[x] != 0) || (isb[x] && !keep);
        o0p[x] = pig[x];
        o1p[x] = nb ? 1.f : 0.f;
        o2p[x] = nd ? 1.f : 0.f;
    }
    *reinterpret_cast<float4*>(out + idx)          = o0;
    *reinterpret_cast<float4*>(out + HW + idx)     = o1;
    *reinterpret_cast<float4*>(out + 2 * HW + idx) = o2;
}

} // namespace

extern "C" void kernel_launch(void* const* d_in, const int* in_sizes, int n_in,
                              void* d_out, int out_size, void* d_ws, size_t ws_size,
                              hipStream_t stream)
{
    (void)in_sizes; (void)n_in; (void)out_size; (void)d_ws; (void)ws_size;
    dim3 grid(W / 1024, H, 1);
    dim3 block(256, 1, 1);
    hipLaunchKernelGGL(wildfire_step, grid, block, 0, stream,
        (const float*)d_in[0],  (const float*)d_in[1],
        (const float*)d_in[2],  (const float*)d_in[3],
        (const float*)d_in[4],
        (const float*)d_in[5],  (const float*)d_in[6],
        (const float*)d_in[7],  (const float*)d_in[8],
        (const float*)d_in[9],
        (const float*)d_in[10], (const float*)d_in[11],
        (const int*)d_in[12],   (const int*)d_in[13],
        (float*)d_out);
}